// Round 14
// baseline (757.855 us; speedup 1.0000x reference)
//
#include <hip/hip_runtime.h>
#include <hip/hip_bf16.h>
#include <cmath>

#define D_MODEL 128
#define NUM_HEAD 4
#define HEAD_DIM 32
#define SEQ 4096
#define BATCH 2
#define QTILE 64   // q-rows per tile (one per lane per tile)
#define NW 8       // waves per attention block (k-split factor)
#define CHUNK 8    // k-rows per staged chunk
#define RROWS 8    // token rows per projection block

__device__ __forceinline__ float tof(float x) { return x; }
__device__ __forceinline__ float tof(__hip_bfloat16 x) { return __bfloat162float(x); }
__device__ __forceinline__ void storef(float* p, size_t i, float v) { p[i] = v; }
__device__ __forceinline__ void storef(__hip_bfloat16* p, size_t i, float v) { p[i] = __float2bfloat16(v); }
__device__ __forceinline__ float4 load4(const float* p) { return *(const float4*)p; }
__device__ __forceinline__ float4 load4(const __hip_bfloat16* p) {
    return make_float4(tof(p[0]), tof(p[1]), tof(p[2]), tof(p[3]));
}

// ---------------------------------------------------------------------------
// Kernel 0: dtype detector (f32 vs bf16 inputs), unchanged (passes since R3).
// ---------------------------------------------------------------------------
__global__ void detect_kernel(const unsigned short* __restrict__ w, int* __restrict__ flag)
{
    const int t = threadIdx.x;   // 64 threads
    int weird = 0;
#pragma unroll
    for (int j = 0; j < 4; ++j) {
        const unsigned short v = w[(t * 4 + j) * 2 + 1];
        const float x = __uint_as_float((unsigned)v << 16);
        const float a = fabsf(x);
        if (a > 1e20f || (a > 0.f && a < 1e-20f)) weird++;
    }
#pragma unroll
    for (int off = 32; off; off >>= 1) weird += __shfl_xor(weird, off);
    if (t == 0) *flag = (weird < 32) ? 1 : 0;
}

// ---------------------------------------------------------------------------
// Kernel 1: x = embedding[seq] + PE;  Q/K/V = x @ W^T  (f32 to workspace)
// ---------------------------------------------------------------------------
template <typename T>
__device__ __forceinline__ void qkv_body(
    const int* __restrict__ seq, const T* __restrict__ emb,
    const T* __restrict__ wq, const T* __restrict__ wk, const T* __restrict__ wv,
    float* __restrict__ Q, float* __restrict__ K, float* __restrict__ V)
{
    const int e = threadIdx.x;               // 0..127 output dim
    const int r0 = blockIdx.x * RROWS;
    __shared__ __align__(16) float xs[RROWS][D_MODEL];

    {
        const int i = e >> 1;
        const double inv = 1.0 / pow(10000.0, (double)i / 64.0);
        const int s0 = r0 & (SEQ - 1);
        double c = cos((double)s0 * inv);
        double s = sin((double)s0 * inv);
        const double cd = cos(inv), sd = sin(inv);
        const bool odd = (e & 1);
#pragma unroll
        for (int r = 0; r < RROWS; ++r) {
            const float pe = (float)(odd ? c : s);
            xs[r][e] = tof(emb[(size_t)seq[r0 + r] * D_MODEL + e]) + pe;
            const double cn = c * cd - s * sd;
            s = s * cd + c * sd;
            c = cn;
        }
    }
    __syncthreads();

    const T* wqr = wq + e * D_MODEL;
    const T* wkr = wk + e * D_MODEL;
    const T* wvr = wv + e * D_MODEL;
    float aq[RROWS], ak[RROWS], av[RROWS];
#pragma unroll
    for (int r = 0; r < RROWS; ++r) { aq[r] = 0.f; ak[r] = 0.f; av[r] = 0.f; }

    for (int c = 0; c < 32; ++c) {
        const float4 wq4 = load4(wqr + 4 * c);
        const float4 wk4 = load4(wkr + 4 * c);
        const float4 wv4 = load4(wvr + 4 * c);
#pragma unroll
        for (int r = 0; r < RROWS; ++r) {
            const float4 x4 = *(const float4*)&xs[r][4*c];
            aq[r] += x4.x*wq4.x + x4.y*wq4.y + x4.z*wq4.z + x4.w*wq4.w;
            ak[r] += x4.x*wk4.x + x4.y*wk4.y + x4.z*wk4.z + x4.w*wk4.w;
            av[r] += x4.x*wv4.x + x4.y*wv4.y + x4.z*wv4.z + x4.w*wv4.w;
        }
    }
#pragma unroll
    for (int r = 0; r < RROWS; ++r) {
        const size_t o = (size_t)(r0 + r) * D_MODEL + e;
        Q[o] = aq[r]; K[o] = ak[r]; V[o] = av[r];
    }
}

__global__ __launch_bounds__(128) void qkv_kernel(
    const int* __restrict__ seq, const void* emb,
    const void* wq, const void* wk, const void* wv,
    float* __restrict__ Q, float* __restrict__ K, float* __restrict__ V,
    const int* __restrict__ flag)
{
    if (*flag)
        qkv_body<float>(seq, (const float*)emb, (const float*)wq,
                        (const float*)wk, (const float*)wv, Q, K, V);
    else
        qkv_body<__hip_bfloat16>(seq, (const __hip_bfloat16*)emb, (const __hip_bfloat16*)wq,
                                 (const __hip_bfloat16*)wk, (const __hip_bfloat16*)wv, Q, K, V);
}

// ---------------------------------------------------------------------------
// Kernel 2 (R14): complementary-pair G=2 attention. Each lane owns row0 from
// big tile (63-by) and row1 from small tile (by). Small tile's causal range
// is a PREFIX of big's, so ONE shared staged K/V stream serves both rows in
// the prefix (16 ds_read_b128 feed 128 FMAs — halves LDS reads per FLOP, the
// R13-diagnosed bottleneck); suffix (chunk-uniform branch) is row0-only.
// Total FMA unchanged (65 units/block); LDS transactions x0.746; 256 blocks
// = 1/CU, per-block wall spread +-6%. launch_bounds(512,1): a 512-thread
// block physically caps at 256 VGPR/wave, so the ~180 live VGPRs fit
// WITHOUT spill ((512,2) would cap at 128 -> R7 spill-storm).
// ---------------------------------------------------------------------------
__global__ __launch_bounds__(512, 1) void attn_kernel(
    const float* __restrict__ Q, const float* __restrict__ K,
    const float* __restrict__ V, float* __restrict__ O)
{
    const int bh = blockIdx.x;              // fast axis -> XCD = bh
    const int by = blockIdx.y;              // 0..31
    const int qt0 = 63 - by;                // big tile
    const int qt1 = by;                     // small tile
    const size_t base = (size_t)(bh >> 2) * SEQ * D_MODEL + (size_t)(bh & 3) * SEQ * HEAD_DIM;
    const float* Qh = Q + base;
    const float* Kh = K + base;
    const float* Vh = V + base;
    float*       Oh = O + base;

    const int tid  = threadIdx.x;
    const int wid  = __builtin_amdgcn_readfirstlane(tid >> 6);
    const int lane = tid & 63;
    const int row0 = qt0 * QTILE + lane;
    const int row1 = qt1 * QTILE + lane;
    const int small_end = (qt1 + 1) * QTILE;   // chunk-aligned (64 % 8 == 0)

    __shared__ __align__(16) float stage[NW][2 * CHUNK * HEAD_DIM];  // 16 KB
    __shared__ float part[NW][2 * QTILE][10];                        // 40 KB

    const float scale = 0.17677669529663687f;   // 1/sqrt(32), folded into Q
    float qv0[32], qv1[32];
#pragma unroll
    for (int j4 = 0; j4 < 8; ++j4) {
        const float4 a = *(const float4*)(Qh + (size_t)row0 * HEAD_DIM + 4 * j4);
        const float4 b = *(const float4*)(Qh + (size_t)row1 * HEAD_DIM + 4 * j4);
        qv0[4*j4] = a.x*scale; qv0[4*j4+1] = a.y*scale; qv0[4*j4+2] = a.z*scale; qv0[4*j4+3] = a.w*scale;
        qv1[4*j4] = b.x*scale; qv1[4*j4+1] = b.y*scale; qv1[4*j4+2] = b.z*scale; qv1[4*j4+3] = b.w*scale;
    }

    float ov0[32], ov1[32];
#pragma unroll
    for (int j = 0; j < 32; ++j) { ov0[j] = 0.f; ov1[j] = 0.f; }
    float m0 = 0.f, l0 = 0.f, m1 = 0.f, l1 = 0.f;

    const int share = (qt0 + 1) * (QTILE / NW); // big-range per-wave k-rows
    const int kbeg  = wid * share;
    const int kend  = kbeg + share;

    // staging roles: lanes 0..31 -> K, lanes 32..63 -> V; 32B each
    const int sl = lane & 31;
    const float* gsrc0 = (lane < 32) ? Kh : Vh;
    float* dst = &stage[wid][((lane >= 32) ? CHUNK * HEAD_DIM : 0) + sl * 8];

    float4 pa, pb;
    {
        const float* src = gsrc0 + (size_t)kbeg * HEAD_DIM + sl * 8;
        pa = *(const float4*)(src);
        pb = *(const float4*)(src + 4);
    }

    for (int k0 = kbeg; k0 < kend; k0 += CHUNK) {
        *(float4*)(dst)     = pa;
        *(float4*)(dst + 4) = pb;
        if (k0 + CHUNK < kend) {
            const float* src = gsrc0 + (size_t)(k0 + CHUNK) * HEAD_DIM + sl * 8;
            pa = *(const float4*)(src);
            pb = *(const float4*)(src + 4);
        }

        if (k0 < small_end) {
            // ======== prefix: both rows share each staged k-row ========
            float p0[CHUNK], p1[CHUNK];
            float cm0 = m0, cm1 = m1;
#pragma unroll
            for (int i = 0; i < CHUNK; ++i) {
                const float* kr = &stage[wid][i * HEAD_DIM];
                float s0 = 0.f, s1 = 0.f;
#pragma unroll
                for (int j4 = 0; j4 < 8; ++j4) {
                    const float4 kk = *(const float4*)(kr + 4 * j4);
                    s0 += qv0[4*j4]*kk.x + qv0[4*j4+1]*kk.y + qv0[4*j4+2]*kk.z + qv0[4*j4+3]*kk.w;
                    s1 += qv1[4*j4]*kk.x + qv1[4*j4+1]*kk.y + qv1[4*j4+2]*kk.z + qv1[4*j4+3]*kk.w;
                }
                const int k = k0 + i;
                p0[i] = (k <= row0) ? fabsf(s0) : -1.f;
                p1[i] = (k <= row1) ? fabsf(s1) : -1.f;
                cm0 = fmaxf(cm0, p0[i]);
                cm1 = fmaxf(cm1, p1[i]);
            }
            const float a0 = __expf(m0 - cm0);
            const float a1 = __expf(m1 - cm1);
            l0 *= a0; m0 = cm0; l1 *= a1; m1 = cm1;
#pragma unroll
            for (int j = 0; j < 32; ++j) { ov0[j] *= a0; ov1[j] *= a1; }
#pragma unroll
            for (int i = 0; i < CHUNK; ++i) {
                const float e0 = (p0[i] >= 0.f) ? __expf(p0[i] - m0) : 0.f;
                const float e1 = (p1[i] >= 0.f) ? __expf(p1[i] - m1) : 0.f;
                l0 += e0; l1 += e1;
                const float* vr = &stage[wid][CHUNK * HEAD_DIM + i * HEAD_DIM];
#pragma unroll
                for (int j4 = 0; j4 < 8; ++j4) {
                    const float4 vv = *(const float4*)(vr + 4 * j4);
                    ov0[4*j4]   += e0 * vv.x; ov0[4*j4+1] += e0 * vv.y;
                    ov0[4*j4+2] += e0 * vv.z; ov0[4*j4+3] += e0 * vv.w;
                    ov1[4*j4]   += e1 * vv.x; ov1[4*j4+1] += e1 * vv.y;
                    ov1[4*j4+2] += e1 * vv.z; ov1[4*j4+3] += e1 * vv.w;
                }
            }
        } else {
            // ======== suffix: row0 only ========
            float p0[CHUNK];
            float cm0 = m0;
#pragma unroll
            for (int i = 0; i < CHUNK; ++i) {
                const float* kr = &stage[wid][i * HEAD_DIM];
                float s0 = 0.f;
#pragma unroll
                for (int j4 = 0; j4 < 8; ++j4) {
                    const float4 kk = *(const float4*)(kr + 4 * j4);
                    s0 += qv0[4*j4]*kk.x + qv0[4*j4+1]*kk.y + qv0[4*j4+2]*kk.z + qv0[4*j4+3]*kk.w;
                }
                const int k = k0 + i;
                p0[i] = (k <= row0) ? fabsf(s0) : -1.f;
                cm0 = fmaxf(cm0, p0[i]);
            }
            const float a0 = __expf(m0 - cm0);
            l0 *= a0; m0 = cm0;
#pragma unroll
            for (int j = 0; j < 32; ++j) ov0[j] *= a0;
#pragma unroll
            for (int i = 0; i < CHUNK; ++i) {
                const float e0 = (p0[i] >= 0.f) ? __expf(p0[i] - m0) : 0.f;
                l0 += e0;
                const float* vr = &stage[wid][CHUNK * HEAD_DIM + i * HEAD_DIM];
#pragma unroll
                for (int j4 = 0; j4 < 8; ++j4) {
                    const float4 vv = *(const float4*)(vr + 4 * j4);
                    ov0[4*j4]   += e0 * vv.x; ov0[4*j4+1] += e0 * vv.y;
                    ov0[4*j4+2] += e0 * vv.z; ov0[4*j4+3] += e0 * vv.w;
                }
            }
        }
    }

    // combine 8 per-wave partials for 128 rows; 4 passes of 8 dims
#pragma unroll
    for (int pass = 0; pass < 4; ++pass) {
        __syncthreads();
#pragma unroll
        for (int j = 0; j < 8; ++j) {
            part[wid][lane][j]         = ov0[pass * 8 + j];
            part[wid][lane + 64][j]    = ov1[pass * 8 + j];
        }
        part[wid][lane][8]      = m0; part[wid][lane][9]      = l0;
        part[wid][lane + 64][8] = m1; part[wid][lane + 64][9] = l1;
        __syncthreads();
        {
            const int r = tid >> 3;        // 0..63
            const int j = tid & 7;
#pragma unroll
            for (int half = 0; half < 2; ++half) {
                const int rr = r + half * 64;
                float M = 0.f;
#pragma unroll
                for (int w = 0; w < NW; ++w) M = fmaxf(M, part[w][rr][8]);
                float lsum = 0.f, osum = 0.f;
#pragma unroll
                for (int w = 0; w < NW; ++w) {
                    const float a = __expf(part[w][rr][8] - M);
                    lsum += a * part[w][rr][9];
                    osum += a * part[w][rr][j];
                }
                const int orow = (half == 0 ? qt0 * QTILE + r : qt1 * QTILE + r);
                Oh[(size_t)orow * HEAD_DIM + pass * 8 + j] = osum / lsum;
            }
        }
    }
}

// ---------------------------------------------------------------------------
// Kernel 3: out = att @ Wo^T  (RROWS=8, float4 weight loads)
// ---------------------------------------------------------------------------
template <typename T>
__device__ __forceinline__ void out_proj_body(
    const float* __restrict__ att, const T* __restrict__ wo, T* __restrict__ out)
{
    const int e = threadIdx.x;
    const int r0 = blockIdx.x * RROWS;
    __shared__ __align__(16) float xs[RROWS][D_MODEL];
#pragma unroll
    for (int r = 0; r < RROWS; ++r)
        xs[r][e] = att[(size_t)(r0 + r) * D_MODEL + e];
    __syncthreads();

    const T* wr = wo + e * D_MODEL;
    float acc[RROWS];
#pragma unroll
    for (int r = 0; r < RROWS; ++r) acc[r] = 0.f;
    for (int c = 0; c < 32; ++c) {
        const float4 w4 = load4(wr + 4 * c);
#pragma unroll
        for (int r = 0; r < RROWS; ++r) {
            const float4 x4 = *(const float4*)&xs[r][4*c];
            acc[r] += x4.x*w4.x + x4.y*w4.y + x4.z*w4.z + x4.w*w4.w;
        }
    }
#pragma unroll
    for (int r = 0; r < RROWS; ++r)
        storef(out, (size_t)(r0 + r) * D_MODEL + e, acc[r]);
}

__global__ __launch_bounds__(128) void out_proj_kernel(
    const float* __restrict__ att, const void* wo, void* out,
    const int* __restrict__ flag)
{
    if (*flag)
        out_proj_body<float>(att, (const float*)wo, (float*)out);
    else
        out_proj_body<__hip_bfloat16>(att, (const __hip_bfloat16*)wo, (__hip_bfloat16*)out);
}

extern "C" void kernel_launch(void* const* d_in, const int* in_sizes, int n_in,
                              void* d_out, int out_size, void* d_ws, size_t ws_size,
                              hipStream_t stream) {
    const int* seq = (const int*)d_in[0];
    const void* emb = d_in[1];
    const void* wq  = d_in[2];
    const void* wk  = d_in[3];
    const void* wv  = d_in[4];
    const void* wo  = d_in[5];

    const size_t N = (size_t)BATCH * SEQ * D_MODEL;   // 1,048,576
    int*   flag = (int*)d_ws;
    float* Q = (float*)((char*)d_ws + 256);
    float* K = Q + N;
    float* V = K + N;
    float* A = Q;   // alias: each attn block reads only its own Q rows first

    detect_kernel<<<dim3(1), dim3(64), 0, stream>>>((const unsigned short*)wq, flag);
    qkv_kernel<<<dim3(BATCH * SEQ / RROWS), dim3(128), 0, stream>>>(seq, emb, wq, wk, wv, Q, K, V, flag);
    attn_kernel<<<dim3(BATCH * NUM_HEAD, SEQ / QTILE / 2), dim3(512), 0, stream>>>(Q, K, V, A);
    out_proj_kernel<<<dim3(BATCH * SEQ / RROWS), dim3(128), 0, stream>>>(A, wo, d_out, flag);
}

// Round 15
// 317.232 us; speedup vs baseline: 2.3890x; 2.3890x over previous
//
#include <hip/hip_runtime.h>
#include <hip/hip_bf16.h>
#include <cmath>

#define D_MODEL 128
#define NUM_HEAD 4
#define HEAD_DIM 32
#define SEQ 4096
#define BATCH 2
#define QTILE 64   // q-rows per tile
#define NW 8       // waves per attention block (k-split factor)
#define CHUNK 8    // k-rows per staged chunk
#define RROWS 8    // token rows per projection block

__device__ __forceinline__ float tof(float x) { return x; }
__device__ __forceinline__ float tof(__hip_bfloat16 x) { return __bfloat162float(x); }
__device__ __forceinline__ void storef(float* p, size_t i, float v) { p[i] = v; }
__device__ __forceinline__ void storef(__hip_bfloat16* p, size_t i, float v) { p[i] = __float2bfloat16(v); }
__device__ __forceinline__ float4 load4(const float* p) { return *(const float4*)p; }
__device__ __forceinline__ float4 load4(const __hip_bfloat16* p) {
    return make_float4(tof(p[0]), tof(p[1]), tof(p[2]), tof(p[3]));
}

// ---------------------------------------------------------------------------
// Kernel 0: dtype detector (f32 vs bf16 inputs), unchanged (passes since R3).
// ---------------------------------------------------------------------------
__global__ void detect_kernel(const unsigned short* __restrict__ w, int* __restrict__ flag)
{
    const int t = threadIdx.x;   // 64 threads
    int weird = 0;
#pragma unroll
    for (int j = 0; j < 4; ++j) {
        const unsigned short v = w[(t * 4 + j) * 2 + 1];
        const float x = __uint_as_float((unsigned)v << 16);
        const float a = fabsf(x);
        if (a > 1e20f || (a > 0.f && a < 1e-20f)) weird++;
    }
#pragma unroll
    for (int off = 32; off; off >>= 1) weird += __shfl_xor(weird, off);
    if (t == 0) *flag = (weird < 32) ? 1 : 0;
}

// ---------------------------------------------------------------------------
// Kernel 1: x = embedding[seq] + PE;  Q/K/V = x @ W^T  (f32 to workspace)
// ---------------------------------------------------------------------------
template <typename T>
__device__ __forceinline__ void qkv_body(
    const int* __restrict__ seq, const T* __restrict__ emb,
    const T* __restrict__ wq, const T* __restrict__ wk, const T* __restrict__ wv,
    float* __restrict__ Q, float* __restrict__ K, float* __restrict__ V)
{
    const int e = threadIdx.x;               // 0..127 output dim
    const int r0 = blockIdx.x * RROWS;
    __shared__ __align__(16) float xs[RROWS][D_MODEL];

    {
        const int i = e >> 1;
        const double inv = 1.0 / pow(10000.0, (double)i / 64.0);
        const int s0 = r0 & (SEQ - 1);
        double c = cos((double)s0 * inv);
        double s = sin((double)s0 * inv);
        const double cd = cos(inv), sd = sin(inv);
        const bool odd = (e & 1);
#pragma unroll
        for (int r = 0; r < RROWS; ++r) {
            const float pe = (float)(odd ? c : s);
            xs[r][e] = tof(emb[(size_t)seq[r0 + r] * D_MODEL + e]) + pe;
            const double cn = c * cd - s * sd;
            s = s * cd + c * sd;
            c = cn;
        }
    }
    __syncthreads();

    const T* wqr = wq + e * D_MODEL;
    const T* wkr = wk + e * D_MODEL;
    const T* wvr = wv + e * D_MODEL;
    float aq[RROWS], ak[RROWS], av[RROWS];
#pragma unroll
    for (int r = 0; r < RROWS; ++r) { aq[r] = 0.f; ak[r] = 0.f; av[r] = 0.f; }

    for (int c = 0; c < 32; ++c) {
        const float4 wq4 = load4(wqr + 4 * c);
        const float4 wk4 = load4(wkr + 4 * c);
        const float4 wv4 = load4(wvr + 4 * c);
#pragma unroll
        for (int r = 0; r < RROWS; ++r) {
            const float4 x4 = *(const float4*)&xs[r][4*c];
            aq[r] += x4.x*wq4.x + x4.y*wq4.y + x4.z*wq4.z + x4.w*wq4.w;
            ak[r] += x4.x*wk4.x + x4.y*wk4.y + x4.z*wk4.z + x4.w*wk4.w;
            av[r] += x4.x*wv4.x + x4.y*wv4.y + x4.z*wv4.z + x4.w*wv4.w;
        }
    }
#pragma unroll
    for (int r = 0; r < RROWS; ++r) {
        const size_t o = (size_t)(r0 + r) * D_MODEL + e;
        Q[o] = aq[r]; K[o] = ak[r]; V[o] = av[r];
    }
}

__global__ __launch_bounds__(128) void qkv_kernel(
    const int* __restrict__ seq, const void* emb,
    const void* wq, const void* wk, const void* wv,
    float* __restrict__ Q, float* __restrict__ K, float* __restrict__ V,
    const int* __restrict__ flag)
{
    if (*flag)
        qkv_body<float>(seq, (const float*)emb, (const float*)wq,
                        (const float*)wk, (const float*)wv, Q, K, V);
    else
        qkv_body<__hip_bfloat16>(seq, (const __hip_bfloat16*)emb, (const __hip_bfloat16*)wq,
                                 (const __hip_bfloat16*)wk, (const __hip_bfloat16*)wv, Q, K, V);
}

// ---------------------------------------------------------------------------
// Kernel 2 (R15): pair-split G=2 attention. Adjacent lane pair (even,odd)
// splits D=32: even owns dims 0..15, odd dims 16..31; each pair serves TWO
// tile rows (pr and pr+32). Per lane: qv 2x16 + ov 2x16 = 64 regs -> ~110
// total, fits the hard 128-VGPR cap (R14's full-width G=2 at ~180 spilled).
// Score = own half-dot + partner half via __shfl_xor(.,1) = DPP quad_perm
// (VALU pipe). DS instr per wave-k-row serving 64 (row,k): 4 K-b128 + 4
// V-b128 = 8 (R12: 16) — halves the LDS-pipe load, the R13-diagnosed wall.
// Each b128 hits 2 addresses across the pair (2-way = conflict-free).
// Staging/prefetch identical to R12; grid = R12's perfectly-paired 256
// blocks (tiles 63-by then by; 65 units/block; 1 block/CU).
// ---------------------------------------------------------------------------
__device__ __forceinline__ void attn_tile_pair(
    int qt, int wid, int lane, int tid,
    const float* __restrict__ Qh, const float* __restrict__ Kh,
    const float* __restrict__ Vh, float* __restrict__ Oh,
    float (*stage)[2 * CHUNK * HEAD_DIM], float (*part)[QTILE][18])
{
    const int half = lane & 1;              // 0: dims 0..15, 1: dims 16..31
    const int pr   = lane >> 1;             // 0..31 pair index
    const int rowA = qt * QTILE + pr;       // head-space rows
    const int rowB = rowA + 32;
    const float scale = 0.17677669529663687f;   // 1/sqrt(32), folded into q

    float qv0[16], qv1[16];
#pragma unroll
    for (int j4 = 0; j4 < 4; ++j4) {
        const float4 a = *(const float4*)(Qh + (size_t)rowA * HEAD_DIM + half * 16 + 4 * j4);
        const float4 b = *(const float4*)(Qh + (size_t)rowB * HEAD_DIM + half * 16 + 4 * j4);
        qv0[4*j4] = a.x*scale; qv0[4*j4+1] = a.y*scale; qv0[4*j4+2] = a.z*scale; qv0[4*j4+3] = a.w*scale;
        qv1[4*j4] = b.x*scale; qv1[4*j4+1] = b.y*scale; qv1[4*j4+2] = b.z*scale; qv1[4*j4+3] = b.w*scale;
    }

    float ov0[16], ov1[16];
#pragma unroll
    for (int j = 0; j < 16; ++j) { ov0[j] = 0.f; ov1[j] = 0.f; }
    float m0 = 0.f, l0 = 0.f, m1 = 0.f, l1 = 0.f;

    const int share = (qt + 1) * (QTILE / NW);
    const int kbeg  = wid * share;
    const int kend  = kbeg + share;

    // staging roles: lanes 0..31 -> K, lanes 32..63 -> V; 32B each
    const int sl = lane & 31;
    const float* gsrc0 = (lane < 32) ? Kh : Vh;
    float* dst = &stage[wid][((lane >= 32) ? CHUNK * HEAD_DIM : 0) + sl * 8];

    float4 pa, pb;
    {
        const float* src = gsrc0 + (size_t)kbeg * HEAD_DIM + sl * 8;
        pa = *(const float4*)(src);
        pb = *(const float4*)(src + 4);
    }

    for (int k0 = kbeg; k0 < kend; k0 += CHUNK) {
        *(float4*)(dst)     = pa;
        *(float4*)(dst + 4) = pb;
        if (k0 + CHUNK < kend) {
            const float* src = gsrc0 + (size_t)(k0 + CHUNK) * HEAD_DIM + sl * 8;
            pa = *(const float4*)(src);
            pb = *(const float4*)(src + 4);
        }

        // ---- QK: each lane half-dots both rows, combine via DPP xor-1 ----
        float p0[CHUNK], p1[CHUNK];
        float cm0 = m0, cm1 = m1;
#pragma unroll
        for (int i = 0; i < CHUNK; ++i) {
            const float* kr = &stage[wid][i * HEAD_DIM + half * 16];
            float s0 = 0.f, s1 = 0.f;
#pragma unroll
            for (int j4 = 0; j4 < 4; ++j4) {
                const float4 kk = *(const float4*)(kr + 4 * j4);
                s0 += qv0[4*j4]*kk.x + qv0[4*j4+1]*kk.y + qv0[4*j4+2]*kk.z + qv0[4*j4+3]*kk.w;
                s1 += qv1[4*j4]*kk.x + qv1[4*j4+1]*kk.y + qv1[4*j4+2]*kk.z + qv1[4*j4+3]*kk.w;
            }
            s0 += __shfl_xor(s0, 1, 64);    // partner half (DPP, VALU pipe)
            s1 += __shfl_xor(s1, 1, 64);
            const int k = k0 + i;
            p0[i] = (k <= rowA) ? fabsf(s0) : -1.f;
            p1[i] = (k <= rowB) ? fabsf(s1) : -1.f;
            cm0 = fmaxf(cm0, p0[i]);
            cm1 = fmaxf(cm1, p1[i]);
        }
        const float a0 = __expf(m0 - cm0);
        const float a1 = __expf(m1 - cm1);
        l0 *= a0; m0 = cm0; l1 *= a1; m1 = cm1;
#pragma unroll
        for (int j = 0; j < 16; ++j) { ov0[j] *= a0; ov1[j] *= a1; }

        // ---- PV: each lane accumulates its 16-dim half for both rows ----
#pragma unroll
        for (int i = 0; i < CHUNK; ++i) {
            const float e0 = (p0[i] >= 0.f) ? __expf(p0[i] - m0) : 0.f;
            const float e1 = (p1[i] >= 0.f) ? __expf(p1[i] - m1) : 0.f;
            l0 += e0; l1 += e1;
            const float* vr = &stage[wid][CHUNK * HEAD_DIM + i * HEAD_DIM + half * 16];
#pragma unroll
            for (int j4 = 0; j4 < 4; ++j4) {
                const float4 vv = *(const float4*)(vr + 4 * j4);
                ov0[4*j4]   += e0 * vv.x; ov0[4*j4+1] += e0 * vv.y;
                ov0[4*j4+2] += e0 * vv.z; ov0[4*j4+3] += e0 * vv.w;
                ov1[4*j4]   += e1 * vv.x; ov1[4*j4+1] += e1 * vv.y;
                ov1[4*j4+2] += e1 * vv.z; ov1[4*j4+3] += e1 * vv.w;
            }
        }
    }

    // ---- combine: 2 half-passes; part[w][row][0..15]=ov half, [16]=m, [17]=l
#pragma unroll
    for (int h = 0; h < 2; ++h) {
        __syncthreads();
        if (half == h) {
#pragma unroll
            for (int j = 0; j < 16; ++j) {
                part[wid][pr][j]      = ov0[j];
                part[wid][pr + 32][j] = ov1[j];
            }
            part[wid][pr][16]      = m0; part[wid][pr][17]      = l0;
            part[wid][pr + 32][16] = m1; part[wid][pr + 32][17] = l1;
        }
        __syncthreads();
        {
            const int r  = tid >> 3;       // 0..63
            const int jj = tid & 7;        // dims jj and jj+8
            float M = 0.f;
#pragma unroll
            for (int w = 0; w < NW; ++w) M = fmaxf(M, part[w][r][16]);
            float lsum = 0.f, o1 = 0.f, o2 = 0.f;
#pragma unroll
            for (int w = 0; w < NW; ++w) {
                const float a = __expf(part[w][r][16] - M);
                lsum += a * part[w][r][17];
                o1   += a * part[w][r][jj];
                o2   += a * part[w][r][jj + 8];
            }
            const size_t orow = (size_t)(qt * QTILE + r) * HEAD_DIM + h * 16;
            Oh[orow + jj]     = o1 / lsum;
            Oh[orow + jj + 8] = o2 / lsum;
        }
    }
}

__global__ __launch_bounds__(512, 2) void attn_kernel(
    const float* __restrict__ Q, const float* __restrict__ K,
    const float* __restrict__ V, float* __restrict__ O)
{
    const int bh = blockIdx.x;              // fast axis -> XCD = bh
    const int by = blockIdx.y;              // 0..31
    const size_t base = (size_t)(bh >> 2) * SEQ * D_MODEL + (size_t)(bh & 3) * SEQ * HEAD_DIM;
    const float* Qh = Q + base;
    const float* Kh = K + base;
    const float* Vh = V + base;
    float*       Oh = O + base;

    const int tid  = threadIdx.x;
    const int wid  = __builtin_amdgcn_readfirstlane(tid >> 6);
    const int lane = tid & 63;

    __shared__ __align__(16) float stage[NW][2 * CHUNK * HEAD_DIM];  // 16 KB
    __shared__ float part[NW][QTILE][18];                            // 36.9 KB

    attn_tile_pair(63 - by, wid, lane, tid, Qh, Kh, Vh, Oh, stage, part);
    attn_tile_pair(by,      wid, lane, tid, Qh, Kh, Vh, Oh, stage, part);
}

// ---------------------------------------------------------------------------
// Kernel 3: out = att @ Wo^T  (RROWS=8, float4 weight loads)
// ---------------------------------------------------------------------------
template <typename T>
__device__ __forceinline__ void out_proj_body(
    const float* __restrict__ att, const T* __restrict__ wo, T* __restrict__ out)
{
    const int e = threadIdx.x;
    const int r0 = blockIdx.x * RROWS;
    __shared__ __align__(16) float xs[RROWS][D_MODEL];
#pragma unroll
    for (int r = 0; r < RROWS; ++r)
        xs[r][e] = att[(size_t)(r0 + r) * D_MODEL + e];
    __syncthreads();

    const T* wr = wo + e * D_MODEL;
    float acc[RROWS];
#pragma unroll
    for (int r = 0; r < RROWS; ++r) acc[r] = 0.f;
    for (int c = 0; c < 32; ++c) {
        const float4 w4 = load4(wr + 4 * c);
#pragma unroll
        for (int r = 0; r < RROWS; ++r) {
            const float4 x4 = *(const float4*)&xs[r][4*c];
            acc[r] += x4.x*w4.x + x4.y*w4.y + x4.z*w4.z + x4.w*w4.w;
        }
    }
#pragma unroll
    for (int r = 0; r < RROWS; ++r)
        storef(out, (size_t)(r0 + r) * D_MODEL + e, acc[r]);
}

__global__ __launch_bounds__(128) void out_proj_kernel(
    const float* __restrict__ att, const void* wo, void* out,
    const int* __restrict__ flag)
{
    if (*flag)
        out_proj_body<float>(att, (const float*)wo, (float*)out);
    else
        out_proj_body<__hip_bfloat16>(att, (const __hip_bfloat16*)wo, (__hip_bfloat16*)out);
}

extern "C" void kernel_launch(void* const* d_in, const int* in_sizes, int n_in,
                              void* d_out, int out_size, void* d_ws, size_t ws_size,
                              hipStream_t stream) {
    const int* seq = (const int*)d_in[0];
    const void* emb = d_in[1];
    const void* wq  = d_in[2];
    const void* wk  = d_in[3];
    const void* wv  = d_in[4];
    const void* wo  = d_in[5];

    const size_t N = (size_t)BATCH * SEQ * D_MODEL;   // 1,048,576
    int*   flag = (int*)d_ws;
    float* Q = (float*)((char*)d_ws + 256);
    float* K = Q + N;
    float* V = K + N;
    float* A = Q;   // alias: each attn tile reads only its own Q rows first

    detect_kernel<<<dim3(1), dim3(64), 0, stream>>>((const unsigned short*)wq, flag);
    qkv_kernel<<<dim3(BATCH * SEQ / RROWS), dim3(128), 0, stream>>>(seq, emb, wq, wk, wv, Q, K, V, flag);
    attn_kernel<<<dim3(BATCH * NUM_HEAD, SEQ / QTILE / 2), dim3(512), 0, stream>>>(Q, K, V, A);
    out_proj_kernel<<<dim3(BATCH * SEQ / RROWS), dim3(128), 0, stream>>>(A, wo, d_out, flag);
}